// Round 3
// baseline (445.734 us; speedup 1.0000x reference)
//
#include <hip/hip_runtime.h>
#include <cstdint>
#include <cmath>

typedef unsigned short u16;
typedef __attribute__((ext_vector_type(4))) float f32x4;
typedef __attribute__((ext_vector_type(8))) short bf16x8;

#define D_MODEL 1024
#define SEQ     2048
#define BATCH   4
#define NHEAD   16
#define MTOT    (BATCH*SEQ)      /* 8192 rows */
#define NXE     ((size_t)MTOT * D_MODEL)   /* 8,388,608 elems per plane */

static_assert(sizeof(bf16x8) == 16, "frag size");

__device__ __forceinline__ float bf2f(u16 u) {
    union { uint32_t i; float f; } v; v.i = ((uint32_t)u) << 16; return v.f;
}
__device__ __forceinline__ u16 f2bf(float x) {
    union { float f; uint32_t i; } v; v.f = x;
    uint32_t r = (v.i + 0x7FFFu + ((v.i >> 16) & 1u)) >> 16;   // RNE
    return (u16)r;
}
__device__ __forceinline__ u16 f2bf_trunc(float x) {          // cheap: P only
    union { float f; uint32_t i; } v; v.f = x;
    return (u16)(v.i >> 16);
}

typedef const __attribute__((address_space(1))) void* gptr_t;
typedef __attribute__((address_space(3))) void* sptr_t;
__device__ __forceinline__ void gload_lds16(const void* g, void* l) {
    __builtin_amdgcn_global_load_lds((gptr_t)g, (sptr_t)l, 16, 0, 0);
}

// extract u16 element e (compile-time const after unroll) from a uint4
__device__ __forceinline__ u16 u4get(const uint4& v, int e) {
    const uint32_t w = ((e >> 1) == 0) ? v.x : ((e >> 1) == 1) ? v.y
                     : ((e >> 1) == 2) ? v.z : v.w;
    return (u16)((e & 1) ? (w >> 16) : (w & 0xFFFFu));
}

// ---------------------------------------------------------------------------
// Precondition-failure flood: d_out is fp32; absmax report encodes 2^e.
// ---------------------------------------------------------------------------
__global__ __launch_bounds__(256) void diag_write(float* __restrict__ out, float v) {
    size_t i = (size_t)blockIdx.x * 256 + threadIdx.x;
    for (; i < NXE; i += (size_t)gridDim.x * 256) out[i] = v;
}

// ---------------------------------------------------------------------------
// Dtype sniffer (validated r3/r5/r6: inputs are fp32 -> flag=0).
// ---------------------------------------------------------------------------
__global__ void detect_dtype(const u16* __restrict__ x, int* __restrict__ flag) {
    __shared__ int cnt;
    if (threadIdx.x == 0) cnt = 0;
    __syncthreads();
    int c = 0;
#pragma unroll
    for (int k = 0; k < 16; ++k) {
        u16 e = x[2 * (threadIdx.x * 16 + k)];
        int ex = (e >> 7) & 0xFF;
        if (e == 0 || (ex >= 100 && ex <= 140)) ++c;
    }
    atomicAdd(&cnt, c);
    __syncthreads();
    if (threadIdx.x == 0) *flag = (cnt >= 3500) ? 1 : 0;
}

// ---------------------------------------------------------------------------
// Normalize inputs to bf16 planes (fp32 -> RNE downconvert; bf16 -> copy).
// ---------------------------------------------------------------------------
struct CvtArgs { const void* src[9]; u16* dst[9]; int n[9]; };

__global__ __launch_bounds__(256) void cvt_all(CvtArgs a, const int* __restrict__ flag) {
    const int seg = blockIdx.y;
    const int n = a.n[seg];
    const int i = (blockIdx.x * 256 + threadIdx.x) * 8;
    if (i >= n) return;
    u16* d = a.dst[seg] + i;
    if (*flag) {
        *(uint4*)d = *(const uint4*)((const u16*)a.src[seg] + i);
    } else {
        const float* s = (const float*)a.src[seg] + i;
        u16 tmp[8];
#pragma unroll
        for (int k = 0; k < 8; ++k) tmp[k] = f2bf(s[k]);
        *(uint4*)d = *(uint4*)tmp;
    }
}

// ---------------------------------------------------------------------------
// MFMA GEMM (m97 structure, 128x128, BK=32) — correctness proven (r6/r7/r8).
// ---------------------------------------------------------------------------
template <typename OutT>
__device__ __forceinline__ void gemm_body(
    const u16* __restrict__ A, const u16* __restrict__ W,
    const u16* __restrict__ bias, OutT* __restrict__ C,
    int M, int N, int K)
{
    __shared__ __align__(16) u16 As[128 * 32];
    __shared__ __align__(16) u16 Bs[128 * 32];

    const int t    = threadIdx.x;
    const int wave = t >> 6;
    const int ln   = t & 15;
    const int qd   = (t >> 4) & 3;
    const int m0   = blockIdx.x * 128;
    const int n0   = blockIdx.y * 128;
    const int wm   = (wave >> 1) * 64;
    const int wn   = (wave & 1) * 64;

    const int srow = t >> 2;
    const int scol = (t & 3) * 8;
    const u16* gA = A + (size_t)(m0 + srow) * K + scol;
    const u16* gB = W + (size_t)(n0 + srow) * K + scol;
    u16* lA = &As[wave * 512];
    u16* lB = &Bs[wave * 512];

    f32x4 acc[4][4] = {};

    for (int k0 = 0; k0 < K; k0 += 32) {
        __syncthreads();
        gload_lds16(gA + k0,                   lA);
        gload_lds16(gA + (size_t)64 * K + k0,  lA + 2048);
        gload_lds16(gB + k0,                   lB);
        gload_lds16(gB + (size_t)64 * K + k0,  lB + 2048);
        __syncthreads();

        bf16x8 af[4], bfr[4];
#pragma unroll
        for (int i = 0; i < 4; ++i)
            af[i] = *(const bf16x8*)&As[(wm + i * 16 + ln) * 32 + qd * 8];
#pragma unroll
        for (int j = 0; j < 4; ++j)
            bfr[j] = *(const bf16x8*)&Bs[(wn + j * 16 + ln) * 32 + qd * 8];
#pragma unroll
        for (int i = 0; i < 4; ++i)
#pragma unroll
            for (int j = 0; j < 4; ++j)
                acc[i][j] = __builtin_amdgcn_mfma_f32_16x16x32_bf16(
                    af[i], bfr[j], acc[i][j], 0, 0, 0);
    }

    float bv[4];
#pragma unroll
    for (int j = 0; j < 4; ++j) bv[j] = bf2f(bias[n0 + wn + j * 16 + ln]);

#pragma unroll
    for (int i = 0; i < 4; ++i)
#pragma unroll
        for (int r = 0; r < 4; ++r) {
            int row = m0 + wm + i * 16 + qd * 4 + r;
            OutT* crow = C + (size_t)row * N + n0 + wn + ln;
#pragma unroll
            for (int j = 0; j < 4; ++j) {
                float v = acc[i][j][r] + bv[j];
                if constexpr (sizeof(OutT) == 2) crow[j * 16] = f2bf(v);
                else                             crow[j * 16] = v;
            }
        }
}

__global__ __launch_bounds__(256) void gemm_qkv(
    const u16* __restrict__ A,
    const u16* __restrict__ W0, const u16* __restrict__ W1, const u16* __restrict__ W2,
    const u16* __restrict__ b0, const u16* __restrict__ b1, const u16* __restrict__ b2,
    u16* __restrict__ C0, u16* __restrict__ C1, u16* __restrict__ C2,
    int M, int N, int K)
{
    const u16* W; const u16* bias; u16* C;
    if (blockIdx.z == 0)      { W = W0; bias = b0; C = C0; }
    else if (blockIdx.z == 1) { W = W1; bias = b1; C = C1; }
    else                      { W = W2; bias = b2; C = C2; }
    gemm_body<u16>(A, W, bias, C, M, N, K);
}

__global__ __launch_bounds__(256) void gemm_final_f32(
    const u16* __restrict__ A, const u16* __restrict__ W,
    const u16* __restrict__ bias, float* __restrict__ C, int M, int N, int K)
{
    gemm_body<float>(A, W, bias, C, M, N, K);
}

// ---------------------------------------------------------------------------
// V transpose: V[b*S+s][h*64+d]  ->  VT[(bh*64+d)][s]   (per-head d-major).
// 64x64 tiles through LDS; ~32 MB total traffic (~6 us).
// ---------------------------------------------------------------------------
__global__ __launch_bounds__(256) void transpose_v(
    const u16* __restrict__ V, u16* __restrict__ VT)
{
    __shared__ u16 T[64][72];           // +8 pad: 144 B row stride (16B-aligned)
    const int st = blockIdx.x;          // s-tile (0..31)
    const int bh = blockIdx.y;          // 0..63
    const int b  = bh >> 4;
    const int h  = bh & 15;
    const int t  = threadIdx.x;

    const int sr = t >> 2;              // local s row 0..63
    const int dc = (t & 3) * 16;        // d chunk 0,16,32,48
    const u16* src = V + ((size_t)b * SEQ + st * 64 + sr) * D_MODEL + h * 64 + dc;
    const uint4 a0 = *(const uint4*)src;
    const uint4 a1 = *(const uint4*)(src + 8);
#pragma unroll
    for (int e = 0; e < 8; ++e) T[dc + e][sr]     = u4get(a0, e);
#pragma unroll
    for (int e = 0; e < 8; ++e) T[dc + 8 + e][sr] = u4get(a1, e);
    __syncthreads();

    const int d  = t >> 2;              // 0..63
    const int sc = (t & 3) * 16;        // 0,16,32,48
    u16* dst = VT + ((size_t)bh * 64 + d) * SEQ + st * 64 + sc;
    *(uint4*)dst       = *(const uint4*)&T[d][sc];
    *(uint4*)(dst + 8) = *(const uint4*)&T[d][sc + 8];
}

// ---------------------------------------------------------------------------
// Flash attention, causal — round 12: 1 wave/block, 32 q-rows, NO LDS V and
// NO barriers.
//   * V consumed via pre-transposed VT[bh][d][s]: PV B-frag = one 16B global
//     load per (ks,j) (replaces 64 scalar ds_read_u16 + pack per iter).
//     V tile data is L1/L2-resident (same 8KB/iter the old staging read).
//   * Psh is wave-private; with no __syncthreads there is no vmcnt(0) drain
//     per iteration -> K/V loads pipeline across iterations (compiler
//     inserts lgkmcnt for the P RAW).
//   * Grid balance kept: qw = (63 - x + y) & 63 (r11 win: per-CU causal
//     lengths mixed; was 30x imbalance).
// Grid: x = 64, y = 64 (b*h); 1 wave/block; LDS 4 KB.
// ---------------------------------------------------------------------------
__global__ __launch_bounds__(64) void flash_attn(
    const u16* __restrict__ Qg, const u16* __restrict__ Kg,
    const u16* __restrict__ VTg, u16* __restrict__ Og)
{
    __shared__ __align__(16) u16 Psh[32 * 64];

    const int lane = threadIdx.x;       // 0..63
    const int ln   = lane & 15;
    const int qd   = lane >> 4;

    const int bh = blockIdx.y;
    const int qw = (63 - (int)blockIdx.x + bh) & 63;   // balance fix
    const int b  = bh >> 4;
    const int h  = bh & 15;
    const int h0 = h * 64;
    const size_t rowBase = (size_t)b * SEQ * D_MODEL;
    const size_t vtBase  = (size_t)bh * 64 * SEQ;
    const int qw0 = qw * 32;
    const int ktMax = qw >> 1;          // last K-tile (only one needing mask)

    // ---- Q fragments straight from global: A[m=ln][k=qd*8+e] ----
    bf16x8 qf[2][2];
#pragma unroll
    for (int i = 0; i < 2; ++i)
#pragma unroll
        for (int ks = 0; ks < 2; ++ks)
            qf[i][ks] = *(const bf16x8*)(Qg + rowBase
                + (size_t)(qw0 + i * 16 + ln) * D_MODEL + h0 + ks * 32 + qd * 8);

    float m_run[2][4], l_run[2][4];
#pragma unroll
    for (int i = 0; i < 2; ++i)
#pragma unroll
        for (int r = 0; r < 4; ++r) { m_run[i][r] = -30000.0f; l_run[i][r] = 0.f; }
    f32x4 oacc[2][4] = {};

    for (int kt = 0; kt <= ktMax; ++kt) {
        // ---- S = Q K^T (K fragments straight from global) ----
        f32x4 sacc[2][4] = {};
#pragma unroll
        for (int ks = 0; ks < 2; ++ks) {
            bf16x8 kf[4];
#pragma unroll
            for (int j = 0; j < 4; ++j)
                kf[j] = *(const bf16x8*)(Kg + rowBase
                    + (size_t)(kt * 64 + j * 16 + ln) * D_MODEL + h0 + ks * 32 + qd * 8);
#pragma unroll
            for (int i = 0; i < 2; ++i)
#pragma unroll
                for (int j = 0; j < 4; ++j)
                    sacc[i][j] = __builtin_amdgcn_mfma_f32_16x16x32_bf16(
                        qf[i][ks], kf[j], sacc[i][j], 0, 0, 0);
        }

        // ---- scale (+ mask on the diagonal tile only) ----
        if (kt == ktMax) {
#pragma unroll
            for (int i = 0; i < 2; ++i)
#pragma unroll
                for (int r = 0; r < 4; ++r) {
                    const int qpos = qw0 + i * 16 + qd * 4 + r;
#pragma unroll
                    for (int j = 0; j < 4; ++j) {
                        const int kpos = kt * 64 + j * 16 + ln;
                        float s = sacc[i][j][r] * 0.125f;
                        sacc[i][j][r] = (kpos > qpos) ? -30000.0f : s;
                    }
                }
        } else {
#pragma unroll
            for (int i = 0; i < 2; ++i)
#pragma unroll
                for (int j = 0; j < 4; ++j)
#pragma unroll
                    for (int r = 0; r < 4; ++r)
                        sacc[i][j][r] *= 0.125f;
        }

        // ---- online softmax (per q-row, stats replicated over 16-lane group) ----
#pragma unroll
        for (int i = 0; i < 2; ++i)
#pragma unroll
            for (int r = 0; r < 4; ++r) {
                float mx = fmaxf(fmaxf(sacc[i][0][r], sacc[i][1][r]),
                                 fmaxf(sacc[i][2][r], sacc[i][3][r]));
                mx = fmaxf(mx, __shfl_xor(mx, 1));
                mx = fmaxf(mx, __shfl_xor(mx, 2));
                mx = fmaxf(mx, __shfl_xor(mx, 4));
                mx = fmaxf(mx, __shfl_xor(mx, 8));

                const float mo = m_run[i][r];
                const float mn = fmaxf(mo, mx);
                const float alpha = __expf(mo - mn);
                m_run[i][r] = mn;
                l_run[i][r] *= alpha;
#pragma unroll
                for (int j = 0; j < 4; ++j) oacc[i][j][r] *= alpha;

                const int prow = i * 16 + qd * 4 + r;         // q row in tile
                const int pswz = qd << 4;                     // ((prow>>2)&3)<<4
                float rs = 0.f;
#pragma unroll
                for (int j = 0; j < 4; ++j) {
                    float p = __expf(sacc[i][j][r] - mn);
                    rs += p;
                    Psh[prow * 64 + ((j * 16 + ln) ^ pswz)] = f2bf_trunc(p);
                }
                rs += __shfl_xor(rs, 1);
                rs += __shfl_xor(rs, 2);
                rs += __shfl_xor(rs, 4);
                rs += __shfl_xor(rs, 8);
                l_run[i][r] += rs;
            }

        // ---- O += P V  (P from LDS; V rows straight from global VT) ----
#pragma unroll
        for (int ks = 0; ks < 2; ++ks) {
            bf16x8 pa[2];                // A-frags of P: row = i*16+ln
#pragma unroll
            for (int i = 0; i < 2; ++i) {
                const int prow = i * 16 + ln;
                const int pswz = ((ln >> 2) & 3) << 4;        // ((prow>>2)&3)<<4
                pa[i] = *(const bf16x8*)&Psh[prow * 64 + ((ks * 32 + qd * 8) ^ pswz)];
            }
#pragma unroll
            for (int j = 0; j < 4; ++j) {
                const bf16x8 vb = *(const bf16x8*)(VTg + vtBase
                    + (size_t)(j * 16 + ln) * SEQ + kt * 64 + ks * 32 + qd * 8);
#pragma unroll
                for (int i = 0; i < 2; ++i)
                    oacc[i][j] = __builtin_amdgcn_mfma_f32_16x16x32_bf16(
                        pa[i], vb, oacc[i][j], 0, 0, 0);
            }
        }
    }

    // ---- epilogue: O / l ----
#pragma unroll
    for (int i = 0; i < 2; ++i)
#pragma unroll
        for (int r = 0; r < 4; ++r) {
            const float inv = 1.f / l_run[i][r];
            const int qrow = qw0 + i * 16 + qd * 4 + r;
            u16* orow = Og + rowBase + (size_t)qrow * D_MODEL + h0 + ln;
#pragma unroll
            for (int j = 0; j < 4; ++j)
                orow[j * 16] = f2bf(oacc[i][j][r] * inv);
        }
}

// ---------------------------------------------------------------------------
static inline bool ranges_overlap(const void* a, size_t an, const void* b, size_t bn) {
    uintptr_t x0 = (uintptr_t)a, x1 = x0 + an;
    uintptr_t y0 = (uintptr_t)b, y1 = y0 + bn;
    return x0 < y1 && y0 < x1;
}

extern "C" void kernel_launch(void* const* d_in, const int* in_sizes, int n_in,
                              void* d_out, int out_size, void* d_ws, size_t ws_size,
                              hipStream_t stream)
{
    int e = 0;
    const int expect[9] = { 8388608, 1048576, 1024, 1048576, 1024,
                            1048576, 1024, 1048576, 1024 };
    if (n_in != 9) e = 59;
    if (!e) for (int i = 0; i < 9; ++i)
        if (in_sizes[i] != expect[i]) { e = 60 + i; break; }
    if (!e && out_size != (int)NXE) e = 53;
    if (!e && ranges_overlap(d_ws, ws_size, d_out, (size_t)out_size * 4)) e = 55;

    const size_t NX = NXE;
    const size_t NW = (size_t)D_MODEL * D_MODEL;
    const size_t NB = D_MODEL;

    // ws need: flag(64) + 4 weights + 4 biases + K + V = 40.0 MB (proven safe r7/r8).
    const size_t need = (64 + 4 * NW + 4 * NB + 2 * NX) * 2;
    if (!e && ws_size < need) e = 50;
    if (e) { diag_write<<<2048, 256, 0, stream>>>((float*)d_out, ldexpf(1.0f, e)); return; }

    // ws layout (u16 elems): flag | Wq Wk Wv Wo | bq bk bv bo | K | V
    u16* ws   = (u16*)d_ws;
    int* flag = (int*)ws;
    u16* Wqb  = ws + 64;
    u16* Wkb  = Wqb + NW;
    u16* Wvb  = Wkb + NW;
    u16* Wob  = Wvb + NW;
    u16* bqb  = Wob + NW;
    u16* bkb  = bqb + NB;
    u16* bvb  = bkb + NB;
    u16* bob  = bvb + NB;
    u16* Kw   = bob + NB;
    u16* Vw   = Kw  + NX;

    // Region lifetimes:
    //   d_out lower 16MB: xb (x bf16; dead after gemm_qkv) -> VT (V transposed)
    //   d_out upper 16MB: Qw
    //   ws Vw: V (dead after transpose_v) -> Ow (attention output)
    //   gemm_final reads Ow (ws) and writes fp32 DIRECTLY to d_out (no memcpy).
    u16* xb  = (u16*)d_out;          // x_bf16; dead after QKV gemm
    u16* Qw  = xb + NX;              // Q plane (upper half)
    u16* VTw = xb;                   // V^T reuses lower half
    u16* Ow  = Vw;                   // attention out over dead V plane

    detect_dtype<<<1, 256, 0, stream>>>((const u16*)d_in[0], flag);

    CvtArgs ca;
    const void* srcs[9] = { d_in[0], d_in[1], d_in[3], d_in[5], d_in[7],
                            d_in[2], d_in[4], d_in[6], d_in[8] };
    u16* dsts[9] = { xb, Wqb, Wkb, Wvb, Wob, bqb, bkb, bvb, bob };
    int  ns[9]   = { (int)NX, (int)NW, (int)NW, (int)NW, (int)NW,
                     (int)NB, (int)NB, (int)NB, (int)NB };
    for (int i = 0; i < 9; ++i) { ca.src[i] = srcs[i]; ca.dst[i] = dsts[i]; ca.n[i] = ns[i]; }
    cvt_all<<<dim3((unsigned)((NX + 2047) / 2048), 9), 256, 0, stream>>>(ca, flag);

    gemm_qkv<<<dim3(MTOT / 128, D_MODEL / 128, 3), 256, 0, stream>>>(
        xb, Wqb, Wkb, Wvb, bqb, bkb, bvb, Qw, Kw, Vw, MTOT, D_MODEL, D_MODEL);

    transpose_v<<<dim3(SEQ / 64, BATCH * NHEAD), 256, 0, stream>>>(Vw, VTw);

    flash_attn<<<dim3(SEQ / 32, BATCH * NHEAD), 64, 0, stream>>>(Qw, Kw, VTw, Ow);

    gemm_final_f32<<<dim3(MTOT / 128, D_MODEL / 128), 256, 0, stream>>>(
        Ow, Wob, bob, (float*)d_out, MTOT, D_MODEL, D_MODEL);
}

// Round 4
// 349.737 us; speedup vs baseline: 1.2745x; 1.2745x over previous
//
#include <hip/hip_runtime.h>
#include <cstdint>
#include <cmath>

typedef unsigned short u16;
typedef __attribute__((ext_vector_type(4))) float f32x4;
typedef __attribute__((ext_vector_type(8))) short bf16x8;

#define D_MODEL 1024
#define SEQ     2048
#define BATCH   4
#define NHEAD   16
#define MTOT    (BATCH*SEQ)      /* 8192 rows */
#define NXE     ((size_t)MTOT * D_MODEL)   /* 8,388,608 elems per plane */

static_assert(sizeof(bf16x8) == 16, "frag size");

__device__ __forceinline__ float bf2f(u16 u) {
    union { uint32_t i; float f; } v; v.i = ((uint32_t)u) << 16; return v.f;
}
__device__ __forceinline__ u16 f2bf(float x) {
    union { float f; uint32_t i; } v; v.f = x;
    uint32_t r = (v.i + 0x7FFFu + ((v.i >> 16) & 1u)) >> 16;   // RNE
    return (u16)r;
}
__device__ __forceinline__ u16 f2bf_trunc(float x) {          // cheap: P only
    union { float f; uint32_t i; } v; v.f = x;
    return (u16)(v.i >> 16);
}

typedef const __attribute__((address_space(1))) void* gptr_t;
typedef __attribute__((address_space(3))) void* sptr_t;
__device__ __forceinline__ void gload_lds16(const void* g, void* l) {
    __builtin_amdgcn_global_load_lds((gptr_t)g, (sptr_t)l, 16, 0, 0);
}

// ---------------------------------------------------------------------------
// Precondition-failure flood: d_out is fp32; absmax report encodes 2^e.
// ---------------------------------------------------------------------------
__global__ __launch_bounds__(256) void diag_write(float* __restrict__ out, float v) {
    size_t i = (size_t)blockIdx.x * 256 + threadIdx.x;
    for (; i < NXE; i += (size_t)gridDim.x * 256) out[i] = v;
}

// ---------------------------------------------------------------------------
// Dtype sniffer (validated r3/r5/r6: inputs are fp32 -> flag=0).
// ---------------------------------------------------------------------------
__global__ void detect_dtype(const u16* __restrict__ x, int* __restrict__ flag) {
    __shared__ int cnt;
    if (threadIdx.x == 0) cnt = 0;
    __syncthreads();
    int c = 0;
#pragma unroll
    for (int k = 0; k < 16; ++k) {
        u16 e = x[2 * (threadIdx.x * 16 + k)];
        int ex = (e >> 7) & 0xFF;
        if (e == 0 || (ex >= 100 && ex <= 140)) ++c;
    }
    atomicAdd(&cnt, c);
    __syncthreads();
    if (threadIdx.x == 0) *flag = (cnt >= 3500) ? 1 : 0;
}

// ---------------------------------------------------------------------------
// Normalize inputs to bf16 planes (fp32 -> RNE downconvert; bf16 -> copy).
// ---------------------------------------------------------------------------
struct CvtArgs { const void* src[9]; u16* dst[9]; int n[9]; };

__global__ __launch_bounds__(256) void cvt_all(CvtArgs a, const int* __restrict__ flag) {
    const int seg = blockIdx.y;
    const int n = a.n[seg];
    const int i = (blockIdx.x * 256 + threadIdx.x) * 8;
    if (i >= n) return;
    u16* d = a.dst[seg] + i;
    if (*flag) {
        *(uint4*)d = *(const uint4*)((const u16*)a.src[seg] + i);
    } else {
        const float* s = (const float*)a.src[seg] + i;
        u16 tmp[8];
#pragma unroll
        for (int k = 0; k < 8; ++k) tmp[k] = f2bf(s[k]);
        *(uint4*)d = *(uint4*)tmp;
    }
}

// ---------------------------------------------------------------------------
// MFMA GEMM (m97 structure, 128x128, BK=32) — correctness proven (r6/r7/r8).
// ---------------------------------------------------------------------------
template <typename OutT>
__device__ __forceinline__ void gemm_body(
    const u16* __restrict__ A, const u16* __restrict__ W,
    const u16* __restrict__ bias, OutT* __restrict__ C,
    int M, int N, int K)
{
    __shared__ __align__(16) u16 As[128 * 32];
    __shared__ __align__(16) u16 Bs[128 * 32];

    const int t    = threadIdx.x;
    const int wave = t >> 6;
    const int ln   = t & 15;
    const int qd   = (t >> 4) & 3;
    const int m0   = blockIdx.x * 128;
    const int n0   = blockIdx.y * 128;
    const int wm   = (wave >> 1) * 64;
    const int wn   = (wave & 1) * 64;

    const int srow = t >> 2;
    const int scol = (t & 3) * 8;
    const u16* gA = A + (size_t)(m0 + srow) * K + scol;
    const u16* gB = W + (size_t)(n0 + srow) * K + scol;
    u16* lA = &As[wave * 512];
    u16* lB = &Bs[wave * 512];

    f32x4 acc[4][4] = {};

    for (int k0 = 0; k0 < K; k0 += 32) {
        __syncthreads();
        gload_lds16(gA + k0,                   lA);
        gload_lds16(gA + (size_t)64 * K + k0,  lA + 2048);
        gload_lds16(gB + k0,                   lB);
        gload_lds16(gB + (size_t)64 * K + k0,  lB + 2048);
        __syncthreads();

        bf16x8 af[4], bfr[4];
#pragma unroll
        for (int i = 0; i < 4; ++i)
            af[i] = *(const bf16x8*)&As[(wm + i * 16 + ln) * 32 + qd * 8];
#pragma unroll
        for (int j = 0; j < 4; ++j)
            bfr[j] = *(const bf16x8*)&Bs[(wn + j * 16 + ln) * 32 + qd * 8];
#pragma unroll
        for (int i = 0; i < 4; ++i)
#pragma unroll
            for (int j = 0; j < 4; ++j)
                acc[i][j] = __builtin_amdgcn_mfma_f32_16x16x32_bf16(
                    af[i], bfr[j], acc[i][j], 0, 0, 0);
    }

    float bv[4];
#pragma unroll
    for (int j = 0; j < 4; ++j) bv[j] = bf2f(bias[n0 + wn + j * 16 + ln]);

#pragma unroll
    for (int i = 0; i < 4; ++i)
#pragma unroll
        for (int r = 0; r < 4; ++r) {
            int row = m0 + wm + i * 16 + qd * 4 + r;
            OutT* crow = C + (size_t)row * N + n0 + wn + ln;
#pragma unroll
            for (int j = 0; j < 4; ++j) {
                float v = acc[i][j][r] + bv[j];
                if constexpr (sizeof(OutT) == 2) crow[j * 16] = f2bf(v);
                else                             crow[j * 16] = v;
            }
        }
}

__global__ __launch_bounds__(256) void gemm_qkv(
    const u16* __restrict__ A,
    const u16* __restrict__ W0, const u16* __restrict__ W1, const u16* __restrict__ W2,
    const u16* __restrict__ b0, const u16* __restrict__ b1, const u16* __restrict__ b2,
    u16* __restrict__ C0, u16* __restrict__ C1, u16* __restrict__ C2,
    int M, int N, int K)
{
    const u16* W; const u16* bias; u16* C;
    if (blockIdx.z == 0)      { W = W0; bias = b0; C = C0; }
    else if (blockIdx.z == 1) { W = W1; bias = b1; C = C1; }
    else                      { W = W2; bias = b2; C = C2; }
    gemm_body<u16>(A, W, bias, C, M, N, K);
}

__global__ __launch_bounds__(256) void gemm_final_f32(
    const u16* __restrict__ A, const u16* __restrict__ W,
    const u16* __restrict__ bias, float* __restrict__ C, int M, int N, int K)
{
    gemm_body<float>(A, W, bias, C, M, N, K);
}

// ---------------------------------------------------------------------------
// Flash attention, causal — round 13: r11 base (206us: LDS V staging via
// global_load_lds, grid balance, 1 wave/block) + SWAPPED QK^T softmax:
//   * sacc[j][i] = mfma(kf[j], qf[i]) computes S^T: lane (qd,ln) reg r holds
//     S[k = kt*64+j*16+qd*4+r][q = qw0+i*16+ln].  All 16 k-values of a
//     q-column are LANE-LOCAL -> row max/sum = in-register reduction +
//     2 shfl_xor(16,32) across qd-groups.  Replaces 64 chained ds_permute
//     per iter (8 rows x 8-deep) with 16 + 8 broadcast shuffles.
//   * P stored transposed-by-lane: 8x ds_write_b64 (packed 4xbf16), swizzle
//     byte pattern Psh[q][k ^ ((q&7)<<3)] -- verified uniform bank spread on
//     both b64 writes and the b128 pa reads (which stay 16B-contiguous since
//     the XOR only flips bits >=3).
//   * oacc rescale / epilogue pick up alpha,l via 4 bpermute broadcasts
//     (__shfl from lane qd*4+r; stats replicated across qd-groups).
// Everything else byte-identical to r11.
// Grid: x = 64, y = 64 (b*h); 1 wave/block; LDS 12 KB.
// ---------------------------------------------------------------------------
__global__ __launch_bounds__(64) void flash_attn(
    const u16* __restrict__ Qg, const u16* __restrict__ Kg,
    const u16* __restrict__ Vg, u16* __restrict__ Og)
{
    __shared__ __align__(16) u16 Vsh[64 * 64];
    __shared__ __align__(16) u16 Psh[32 * 64];

    const int lane = threadIdx.x;       // 0..63
    const int ln   = lane & 15;
    const int qd   = lane >> 4;
    const int psw  = (ln & 7) << 3;     // P swizzle (u16 elems)

    const int bh = blockIdx.y;
    const int qw = (63 - (int)blockIdx.x + bh) & 63;   // balance fix (r11)
    const int b  = bh >> 4;
    const int h  = bh & 15;
    const int h0 = h * 64;
    const size_t rowBase = (size_t)b * SEQ * D_MODEL;
    const int qw0 = qw * 32;
    const int ktMax = qw >> 1;          // last K-tile (only one needing mask)

    // V staging source coords (per-lane; dest is linear lane*16B per call)
    const int vrL = lane >> 3;          // 0..7
    const int vcL = (lane & 7) * 8;     // 0,8,..,56

    // ---- Q fragments straight from global: B-frag [n=q=ln][k=qd*8+e] ----
    bf16x8 qf[2][2];
#pragma unroll
    for (int i = 0; i < 2; ++i)
#pragma unroll
        for (int ks = 0; ks < 2; ++ks)
            qf[i][ks] = *(const bf16x8*)(Qg + rowBase
                + (size_t)(qw0 + i * 16 + ln) * D_MODEL + h0 + ks * 32 + qd * 8);

    float m_run[2], l_run[2];
#pragma unroll
    for (int i = 0; i < 2; ++i) { m_run[i] = -30000.0f; l_run[i] = 0.f; }
    f32x4 oacc[2][4] = {};

    for (int kt = 0; kt <= ktMax; ++kt) {
        __syncthreads();                 // prev iter's Vsh/Psh reads done
        // ---- stage V tile (64x64) async; source col pre-swizzled ----
        {
            const u16* vbase = Vg + rowBase
                + (size_t)(kt * 64 + vrL) * D_MODEL + h0;
#pragma unroll
            for (int p = 0; p < 8; ++p)
                gload_lds16(vbase + (size_t)(p * 8) * D_MODEL
                                  + (vcL ^ ((p & 3) << 4)),
                            &Vsh[p * 512]);
        }

        // ---- S^T = K Q^T (K fragments straight from global) ----
        f32x4 sacc[4][2] = {};
#pragma unroll
        for (int ks = 0; ks < 2; ++ks) {
            bf16x8 kf[4];
#pragma unroll
            for (int j = 0; j < 4; ++j)
                kf[j] = *(const bf16x8*)(Kg + rowBase
                    + (size_t)(kt * 64 + j * 16 + ln) * D_MODEL + h0 + ks * 32 + qd * 8);
#pragma unroll
            for (int j = 0; j < 4; ++j)
#pragma unroll
                for (int i = 0; i < 2; ++i)
                    sacc[j][i] = __builtin_amdgcn_mfma_f32_16x16x32_bf16(
                        kf[j], qf[i][ks], sacc[j][i], 0, 0, 0);
        }

        // ---- scale (+ mask on the diagonal tile only) ----
        if (kt == ktMax) {
#pragma unroll
            for (int j = 0; j < 4; ++j)
#pragma unroll
                for (int r = 0; r < 4; ++r) {
                    const int kpos = kt * 64 + j * 16 + qd * 4 + r;
#pragma unroll
                    for (int i = 0; i < 2; ++i) {
                        const int qpos = qw0 + i * 16 + ln;
                        float s = sacc[j][i][r] * 0.125f;
                        sacc[j][i][r] = (kpos > qpos) ? -30000.0f : s;
                    }
                }
        } else {
#pragma unroll
            for (int j = 0; j < 4; ++j)
#pragma unroll
                for (int i = 0; i < 2; ++i)
#pragma unroll
                    for (int r = 0; r < 4; ++r)
                        sacc[j][i][r] *= 0.125f;
        }

        // ---- online softmax: lane-local over 16 regs + 2 shfl per reduce ----
#pragma unroll
        for (int i = 0; i < 2; ++i) {
            float mx = sacc[0][i][0];
#pragma unroll
            for (int j = 0; j < 4; ++j)
#pragma unroll
                for (int r = 0; r < 4; ++r) mx = fmaxf(mx, sacc[j][i][r]);
            mx = fmaxf(mx, __shfl_xor(mx, 16));
            mx = fmaxf(mx, __shfl_xor(mx, 32));

            const float mo = m_run[i];
            const float mn = fmaxf(mo, mx);
            const float alpha = __expf(mo - mn);
            m_run[i] = mn;

            float rs = 0.f;
#pragma unroll
            for (int j = 0; j < 4; ++j) {
                u16 tp[4];
#pragma unroll
                for (int r = 0; r < 4; ++r) {
                    float p = __expf(sacc[j][i][r] - mn);
                    rs += p;
                    tp[r] = f2bf_trunc(p);
                }
                uint2 w;
                w.x = (uint32_t)tp[0] | ((uint32_t)tp[1] << 16);
                w.y = (uint32_t)tp[2] | ((uint32_t)tp[3] << 16);
                *(uint2*)&Psh[(i * 16 + ln) * 64 + ((j * 16 + qd * 4) ^ psw)] = w;
            }
            rs += __shfl_xor(rs, 16);
            rs += __shfl_xor(rs, 32);
            l_run[i] = l_run[i] * alpha + rs;

            // rescale O rows (row = qd*4+r; alpha lives at lane ln'=qd*4+r)
#pragma unroll
            for (int r = 0; r < 4; ++r) {
                const float ar = __shfl(alpha, qd * 4 + r);
#pragma unroll
                for (int j = 0; j < 4; ++j) oacc[i][j][r] *= ar;
            }
        }

        __syncthreads();                 // V staged (vmcnt) + P visible

        // ---- O += P V ----
#pragma unroll
        for (int ks = 0; ks < 2; ++ks) {
            bf16x8 pa[2];                // A-frags of P: row = q = i*16+ln
#pragma unroll
            for (int i = 0; i < 2; ++i)
                pa[i] = *(const bf16x8*)&Psh[(i * 16 + ln) * 64
                                             + ((ks * 32 + qd * 8) ^ psw)];
#pragma unroll
            for (int j = 0; j < 4; ++j) {
                const int vswz = qd << 4;   // ((k>>3)&3)<<4, k = ks*32+qd*8+e
                bf16x8 vb;                  // B-frag of V: n = d = j*16+ln
#pragma unroll
                for (int e = 0; e < 8; ++e)
                    vb[e] = (short)Vsh[(ks * 32 + qd * 8 + e) * 64
                                       + ((j * 16 + ln) ^ vswz)];
#pragma unroll
                for (int i = 0; i < 2; ++i)
                    oacc[i][j] = __builtin_amdgcn_mfma_f32_16x16x32_bf16(
                        pa[i], vb, oacc[i][j], 0, 0, 0);
            }
        }
    }

    // ---- epilogue: O / l  (l lives at lane ln'=qd*4+r, bpermute it in) ----
#pragma unroll
    for (int i = 0; i < 2; ++i)
#pragma unroll
        for (int r = 0; r < 4; ++r) {
            const float lr = __shfl(l_run[i], qd * 4 + r);
            const float inv = 1.f / lr;
            const int qrow = qw0 + i * 16 + qd * 4 + r;
            u16* orow = Og + rowBase + (size_t)qrow * D_MODEL + h0 + ln;
#pragma unroll
            for (int j = 0; j < 4; ++j)
                orow[j * 16] = f2bf(oacc[i][j][r] * inv);
        }
}

// ---------------------------------------------------------------------------
static inline bool ranges_overlap(const void* a, size_t an, const void* b, size_t bn) {
    uintptr_t x0 = (uintptr_t)a, x1 = x0 + an;
    uintptr_t y0 = (uintptr_t)b, y1 = y0 + bn;
    return x0 < y1 && y0 < x1;
}

extern "C" void kernel_launch(void* const* d_in, const int* in_sizes, int n_in,
                              void* d_out, int out_size, void* d_ws, size_t ws_size,
                              hipStream_t stream)
{
    int e = 0;
    const int expect[9] = { 8388608, 1048576, 1024, 1048576, 1024,
                            1048576, 1024, 1048576, 1024 };
    if (n_in != 9) e = 59;
    if (!e) for (int i = 0; i < 9; ++i)
        if (in_sizes[i] != expect[i]) { e = 60 + i; break; }
    if (!e && out_size != (int)NXE) e = 53;
    if (!e && ranges_overlap(d_ws, ws_size, d_out, (size_t)out_size * 4)) e = 55;

    const size_t NX = NXE;
    const size_t NW = (size_t)D_MODEL * D_MODEL;
    const size_t NB = D_MODEL;

    // ws need: flag(64) + 4 weights + 4 biases + K + V = 40.0 MB (proven safe r7/r8).
    const size_t need = (64 + 4 * NW + 4 * NB + 2 * NX) * 2;
    if (!e && ws_size < need) e = 50;
    if (e) { diag_write<<<2048, 256, 0, stream>>>((float*)d_out, ldexpf(1.0f, e)); return; }

    // ws layout (u16 elems): flag | Wq Wk Wv Wo | bq bk bv bo | K | V
    u16* ws   = (u16*)d_ws;
    int* flag = (int*)ws;
    u16* Wqb  = ws + 64;
    u16* Wkb  = Wqb + NW;
    u16* Wvb  = Wkb + NW;
    u16* Wob  = Wvb + NW;
    u16* bqb  = Wob + NW;
    u16* bkb  = bqb + NB;
    u16* bvb  = bkb + NB;
    u16* bob  = bvb + NB;
    u16* Kw   = bob + NB;
    u16* Vw   = Kw  + NX;

    // d_out (32 MB) packing: [xb / A : 16 MB][Q : 16 MB].
    u16* xb = (u16*)d_out;           // x_bf16; dead after QKV gemm
    u16* Qw = xb + NX;               // Q plane (upper half)
    u16* Aw = xb;                    // attention out reuses lower half
    float* Fout = (float*)Kw;        // final fp32 out over dead K+V (32 MB)

    detect_dtype<<<1, 256, 0, stream>>>((const u16*)d_in[0], flag);

    CvtArgs ca;
    const void* srcs[9] = { d_in[0], d_in[1], d_in[3], d_in[5], d_in[7],
                            d_in[2], d_in[4], d_in[6], d_in[8] };
    u16* dsts[9] = { xb, Wqb, Wkb, Wvb, Wob, bqb, bkb, bvb, bob };
    int  ns[9]   = { (int)NX, (int)NW, (int)NW, (int)NW, (int)NW,
                     (int)NB, (int)NB, (int)NB, (int)NB };
    for (int i = 0; i < 9; ++i) { ca.src[i] = srcs[i]; ca.dst[i] = dsts[i]; ca.n[i] = ns[i]; }
    cvt_all<<<dim3((unsigned)((NX + 2047) / 2048), 9), 256, 0, stream>>>(ca, flag);

    gemm_qkv<<<dim3(MTOT / 128, D_MODEL / 128, 3), 256, 0, stream>>>(
        xb, Wqb, Wkb, Wvb, bqb, bkb, bvb, Qw, Kw, Vw, MTOT, D_MODEL, D_MODEL);

    flash_attn<<<dim3(SEQ / 32, BATCH * NHEAD), 64, 0, stream>>>(Qw, Kw, Vw, Aw);

    gemm_final_f32<<<dim3(MTOT / 128, D_MODEL / 128), 256, 0, stream>>>(
        Aw, Wob, bob, Fout, MTOT, D_MODEL, D_MODEL);

    hipMemcpyAsync(d_out, Fout, NX * sizeof(float), hipMemcpyDeviceToDevice, stream);
}

// Round 5
// 338.614 us; speedup vs baseline: 1.3163x; 1.0328x over previous
//
#include <hip/hip_runtime.h>
#include <cstdint>
#include <cmath>

typedef unsigned short u16;
typedef __attribute__((ext_vector_type(4))) float f32x4;
typedef __attribute__((ext_vector_type(8))) short bf16x8;

#define D_MODEL 1024
#define SEQ     2048
#define BATCH   4
#define NHEAD   16
#define MTOT    (BATCH*SEQ)      /* 8192 rows */
#define NXE     ((size_t)MTOT * D_MODEL)   /* 8,388,608 elems per plane */

static_assert(sizeof(bf16x8) == 16, "frag size");

__device__ __forceinline__ float bf2f(u16 u) {
    union { uint32_t i; float f; } v; v.i = ((uint32_t)u) << 16; return v.f;
}
__device__ __forceinline__ u16 f2bf(float x) {
    union { float f; uint32_t i; } v; v.f = x;
    uint32_t r = (v.i + 0x7FFFu + ((v.i >> 16) & 1u)) >> 16;   // RNE
    return (u16)r;
}
__device__ __forceinline__ u16 f2bf_trunc(float x) {          // cheap: P only
    union { float f; uint32_t i; } v; v.f = x;
    return (u16)(v.i >> 16);
}

typedef const __attribute__((address_space(1))) void* gptr_t;
typedef __attribute__((address_space(3))) void* sptr_t;
__device__ __forceinline__ void gload_lds16(const void* g, void* l) {
    __builtin_amdgcn_global_load_lds((gptr_t)g, (sptr_t)l, 16, 0, 0);
}

// extract u16 element e (compile-time const after unroll) from a uint4
__device__ __forceinline__ u16 u4get(const uint4& v, int e) {
    const uint32_t w = ((e >> 1) == 0) ? v.x : ((e >> 1) == 1) ? v.y
                     : ((e >> 1) == 2) ? v.z : v.w;
    return (u16)((e & 1) ? (w >> 16) : (w & 0xFFFFu));
}

// ---------------------------------------------------------------------------
// Precondition-failure flood: d_out is fp32; absmax report encodes 2^e.
// ---------------------------------------------------------------------------
__global__ __launch_bounds__(256) void diag_write(float* __restrict__ out, float v) {
    size_t i = (size_t)blockIdx.x * 256 + threadIdx.x;
    for (; i < NXE; i += (size_t)gridDim.x * 256) out[i] = v;
}

// ---------------------------------------------------------------------------
// Dtype sniffer (validated r3/r5/r6: inputs are fp32 -> flag=0).
// ---------------------------------------------------------------------------
__global__ void detect_dtype(const u16* __restrict__ x, int* __restrict__ flag) {
    __shared__ int cnt;
    if (threadIdx.x == 0) cnt = 0;
    __syncthreads();
    int c = 0;
#pragma unroll
    for (int k = 0; k < 16; ++k) {
        u16 e = x[2 * (threadIdx.x * 16 + k)];
        int ex = (e >> 7) & 0xFF;
        if (e == 0 || (ex >= 100 && ex <= 140)) ++c;
    }
    atomicAdd(&cnt, c);
    __syncthreads();
    if (threadIdx.x == 0) *flag = (cnt >= 3500) ? 1 : 0;
}

// ---------------------------------------------------------------------------
// Normalize inputs to bf16 planes (fp32 -> RNE downconvert; bf16 -> copy).
// ---------------------------------------------------------------------------
struct CvtArgs { const void* src[9]; u16* dst[9]; int n[9]; };

__global__ __launch_bounds__(256) void cvt_all(CvtArgs a, const int* __restrict__ flag) {
    const int seg = blockIdx.y;
    const int n = a.n[seg];
    const int i = (blockIdx.x * 256 + threadIdx.x) * 8;
    if (i >= n) return;
    u16* d = a.dst[seg] + i;
    if (*flag) {
        *(uint4*)d = *(const uint4*)((const u16*)a.src[seg] + i);
    } else {
        const float* s = (const float*)a.src[seg] + i;
        u16 tmp[8];
#pragma unroll
        for (int k = 0; k < 8; ++k) tmp[k] = f2bf(s[k]);
        *(uint4*)d = *(uint4*)tmp;
    }
}

// ---------------------------------------------------------------------------
// MFMA GEMM (m97 structure, 128x128, BK=32) — correctness proven (r6/r7/r8).
// ---------------------------------------------------------------------------
template <typename OutT>
__device__ __forceinline__ void gemm_body(
    const u16* __restrict__ A, const u16* __restrict__ W,
    const u16* __restrict__ bias, OutT* __restrict__ C,
    int M, int N, int K)
{
    __shared__ __align__(16) u16 As[128 * 32];
    __shared__ __align__(16) u16 Bs[128 * 32];

    const int t    = threadIdx.x;
    const int wave = t >> 6;
    const int ln   = t & 15;
    const int qd   = (t >> 4) & 3;
    const int m0   = blockIdx.x * 128;
    const int n0   = blockIdx.y * 128;
    const int wm   = (wave >> 1) * 64;
    const int wn   = (wave & 1) * 64;

    const int srow = t >> 2;
    const int scol = (t & 3) * 8;
    const u16* gA = A + (size_t)(m0 + srow) * K + scol;
    const u16* gB = W + (size_t)(n0 + srow) * K + scol;
    u16* lA = &As[wave * 512];
    u16* lB = &Bs[wave * 512];

    f32x4 acc[4][4] = {};

    for (int k0 = 0; k0 < K; k0 += 32) {
        __syncthreads();
        gload_lds16(gA + k0,                   lA);
        gload_lds16(gA + (size_t)64 * K + k0,  lA + 2048);
        gload_lds16(gB + k0,                   lB);
        gload_lds16(gB + (size_t)64 * K + k0,  lB + 2048);
        __syncthreads();

        bf16x8 af[4], bfr[4];
#pragma unroll
        for (int i = 0; i < 4; ++i)
            af[i] = *(const bf16x8*)&As[(wm + i * 16 + ln) * 32 + qd * 8];
#pragma unroll
        for (int j = 0; j < 4; ++j)
            bfr[j] = *(const bf16x8*)&Bs[(wn + j * 16 + ln) * 32 + qd * 8];
#pragma unroll
        for (int i = 0; i < 4; ++i)
#pragma unroll
            for (int j = 0; j < 4; ++j)
                acc[i][j] = __builtin_amdgcn_mfma_f32_16x16x32_bf16(
                    af[i], bfr[j], acc[i][j], 0, 0, 0);
    }

    float bv[4];
#pragma unroll
    for (int j = 0; j < 4; ++j) bv[j] = bf2f(bias[n0 + wn + j * 16 + ln]);

#pragma unroll
    for (int i = 0; i < 4; ++i)
#pragma unroll
        for (int r = 0; r < 4; ++r) {
            int row = m0 + wm + i * 16 + qd * 4 + r;
            OutT* crow = C + (size_t)row * N + n0 + wn + ln;
#pragma unroll
            for (int j = 0; j < 4; ++j) {
                float v = acc[i][j][r] + bv[j];
                if constexpr (sizeof(OutT) == 2) crow[j * 16] = f2bf(v);
                else                             crow[j * 16] = v;
            }
        }
}

__global__ __launch_bounds__(256) void gemm_qkv(
    const u16* __restrict__ A,
    const u16* __restrict__ W0, const u16* __restrict__ W1, const u16* __restrict__ W2,
    const u16* __restrict__ b0, const u16* __restrict__ b1, const u16* __restrict__ b2,
    u16* __restrict__ C0, u16* __restrict__ C1, u16* __restrict__ C2,
    int M, int N, int K)
{
    const u16* W; const u16* bias; u16* C;
    if (blockIdx.z == 0)      { W = W0; bias = b0; C = C0; }
    else if (blockIdx.z == 1) { W = W1; bias = b1; C = C1; }
    else                      { W = W2; bias = b2; C = C2; }
    gemm_body<u16>(A, W, bias, C, M, N, K);
}

__global__ __launch_bounds__(256) void gemm_final_f32(
    const u16* __restrict__ A, const u16* __restrict__ W,
    const u16* __restrict__ bias, float* __restrict__ C, int M, int N, int K)
{
    gemm_body<float>(A, W, bias, C, M, N, K);
}

// ---------------------------------------------------------------------------
// V transpose: V[b*S+s][h*64+d]  ->  VT[(bh*64+d)][s]   (per-head d-major).
// 64x64 tiles through LDS; ~32 MB total traffic (~6 us). Proven correct (r12).
// ---------------------------------------------------------------------------
__global__ __launch_bounds__(256) void transpose_v(
    const u16* __restrict__ V, u16* __restrict__ VT)
{
    __shared__ u16 T[64][72];           // +8 pad: 144 B row stride (16B-aligned)
    const int st = blockIdx.x;          // s-tile (0..31)
    const int bh = blockIdx.y;          // 0..63
    const int b  = bh >> 4;
    const int h  = bh & 15;
    const int t  = threadIdx.x;

    const int sr = t >> 2;              // local s row 0..63
    const int dc = (t & 3) * 16;        // d chunk 0,16,32,48
    const u16* src = V + ((size_t)b * SEQ + st * 64 + sr) * D_MODEL + h * 64 + dc;
    const uint4 a0 = *(const uint4*)src;
    const uint4 a1 = *(const uint4*)(src + 8);
#pragma unroll
    for (int e = 0; e < 8; ++e) T[dc + e][sr]     = u4get(a0, e);
#pragma unroll
    for (int e = 0; e < 8; ++e) T[dc + 8 + e][sr] = u4get(a1, e);
    __syncthreads();

    const int d  = t >> 2;              // 0..63
    const int sc = (t & 3) * 16;        // 0,16,32,48
    u16* dst = VT + ((size_t)bh * 64 + d) * SEQ + st * 64 + sc;
    *(uint4*)dst       = *(const uint4*)&T[d][sc];
    *(uint4*)(dst + 8) = *(const uint4*)&T[d][sc + 8];
}

// ---------------------------------------------------------------------------
// Flash attention, causal — round 14: r13 (swapped QK^T, lane-local softmax,
// 152us) + VECTORIZED PV V-reads:
//   * V pre-transposed once (transpose_v) to VT[bh*64+d][s].
//   * Per kt: stage 64d x 64s VT tile into LDS via global_load_lds, source
//     column pre-XOR-swizzled with swz(d) = (d&7)<<3 (8-u16 granule = the
//     16B load granule, so chunks stay intact):
//       VsL[d][x] = VT[bh*64+d][kt*64 + (x ^ swz(d))]
//   * PV B-frag = ONE ds_read_b128 per (ks,j):
//       row d = j*16+ln, col (ks*32+qd*8) ^ ((ln&7)<<3)
//     Bank walk: lanes spread over all 32 banks at the b128 minimum
//     (8 cyc/wave) -> conflict-free.  Replaces 64 ds_read_u16 + 64 pack
//     VALU per iter (the dominant serial cost at r13).
// Everything else identical to r13. Grid: x=64, y=64; 1 wave/block; 12KB LDS.
// ---------------------------------------------------------------------------
__global__ __launch_bounds__(64) void flash_attn(
    const u16* __restrict__ Qg, const u16* __restrict__ Kg,
    const u16* __restrict__ VTg, u16* __restrict__ Og)
{
    __shared__ __align__(16) u16 Vsh[64 * 64];   // VT tile, swizzled
    __shared__ __align__(16) u16 Psh[32 * 64];

    const int lane = threadIdx.x;       // 0..63
    const int ln   = lane & 15;
    const int qd   = lane >> 4;
    const int psw  = (ln & 7) << 3;     // P swizzle (u16 elems)

    const int bh = blockIdx.y;
    const int qw = (63 - (int)blockIdx.x + bh) & 63;   // balance fix (r11)
    const int b  = bh >> 4;
    const int h  = bh & 15;
    const int h0 = h * 64;
    const size_t rowBase = (size_t)b * SEQ * D_MODEL;
    const int qw0 = qw * 32;
    const int ktMax = qw >> 1;          // last K-tile (only one needing mask)

    // VT staging source coords (dest is linear lane*16B per call):
    //   call p fills rows d = p*8 + (lane>>3), chunk cc = lane&7.
    //   source col = kt*64 + ((cc*8) ^ ((d&7)<<3)), d&7 = lane>>3.
    const int vdG = lane >> 3;          // 0..7 (= d&7 for every call)
    const int vsw = ((lane & 7) * 8) ^ (vdG << 3);
    const u16* vtRow0 = VTg + ((size_t)(bh * 64 + vdG)) * SEQ + vsw;

    // ---- Q fragments straight from global: B-frag [n=q=ln][k=qd*8+e] ----
    bf16x8 qf[2][2];
#pragma unroll
    for (int i = 0; i < 2; ++i)
#pragma unroll
        for (int ks = 0; ks < 2; ++ks)
            qf[i][ks] = *(const bf16x8*)(Qg + rowBase
                + (size_t)(qw0 + i * 16 + ln) * D_MODEL + h0 + ks * 32 + qd * 8);

    float m_run[2], l_run[2];
#pragma unroll
    for (int i = 0; i < 2; ++i) { m_run[i] = -30000.0f; l_run[i] = 0.f; }
    f32x4 oacc[2][4] = {};

    for (int kt = 0; kt <= ktMax; ++kt) {
        __syncthreads();                 // prev iter's Vsh/Psh reads done
        // ---- stage VT tile (64d x 64s) async; source col pre-swizzled ----
        {
            const u16* vbase = vtRow0 + kt * 64;
#pragma unroll
            for (int p = 0; p < 8; ++p)
                gload_lds16(vbase + (size_t)(p * 8) * SEQ, &Vsh[p * 512]);
        }

        // ---- S^T = K Q^T (K fragments straight from global) ----
        f32x4 sacc[4][2] = {};
#pragma unroll
        for (int ks = 0; ks < 2; ++ks) {
            bf16x8 kf[4];
#pragma unroll
            for (int j = 0; j < 4; ++j)
                kf[j] = *(const bf16x8*)(Kg + rowBase
                    + (size_t)(kt * 64 + j * 16 + ln) * D_MODEL + h0 + ks * 32 + qd * 8);
#pragma unroll
            for (int j = 0; j < 4; ++j)
#pragma unroll
                for (int i = 0; i < 2; ++i)
                    sacc[j][i] = __builtin_amdgcn_mfma_f32_16x16x32_bf16(
                        kf[j], qf[i][ks], sacc[j][i], 0, 0, 0);
        }

        // ---- scale (+ mask on the diagonal tile only) ----
        if (kt == ktMax) {
#pragma unroll
            for (int j = 0; j < 4; ++j)
#pragma unroll
                for (int r = 0; r < 4; ++r) {
                    const int kpos = kt * 64 + j * 16 + qd * 4 + r;
#pragma unroll
                    for (int i = 0; i < 2; ++i) {
                        const int qpos = qw0 + i * 16 + ln;
                        float s = sacc[j][i][r] * 0.125f;
                        sacc[j][i][r] = (kpos > qpos) ? -30000.0f : s;
                    }
                }
        } else {
#pragma unroll
            for (int j = 0; j < 4; ++j)
#pragma unroll
                for (int i = 0; i < 2; ++i)
#pragma unroll
                    for (int r = 0; r < 4; ++r)
                        sacc[j][i][r] *= 0.125f;
        }

        // ---- online softmax: lane-local over 16 regs + 2 shfl per reduce ----
#pragma unroll
        for (int i = 0; i < 2; ++i) {
            float mx = sacc[0][i][0];
#pragma unroll
            for (int j = 0; j < 4; ++j)
#pragma unroll
                for (int r = 0; r < 4; ++r) mx = fmaxf(mx, sacc[j][i][r]);
            mx = fmaxf(mx, __shfl_xor(mx, 16));
            mx = fmaxf(mx, __shfl_xor(mx, 32));

            const float mo = m_run[i];
            const float mn = fmaxf(mo, mx);
            const float alpha = __expf(mo - mn);
            m_run[i] = mn;

            float rs = 0.f;
#pragma unroll
            for (int j = 0; j < 4; ++j) {
                u16 tp[4];
#pragma unroll
                for (int r = 0; r < 4; ++r) {
                    float p = __expf(sacc[j][i][r] - mn);
                    rs += p;
                    tp[r] = f2bf_trunc(p);
                }
                uint2 w;
                w.x = (uint32_t)tp[0] | ((uint32_t)tp[1] << 16);
                w.y = (uint32_t)tp[2] | ((uint32_t)tp[3] << 16);
                *(uint2*)&Psh[(i * 16 + ln) * 64 + ((j * 16 + qd * 4) ^ psw)] = w;
            }
            rs += __shfl_xor(rs, 16);
            rs += __shfl_xor(rs, 32);
            l_run[i] = l_run[i] * alpha + rs;

            // rescale O rows (row = qd*4+r; alpha lives at lane ln'=qd*4+r)
#pragma unroll
            for (int r = 0; r < 4; ++r) {
                const float ar = __shfl(alpha, qd * 4 + r);
#pragma unroll
                for (int j = 0; j < 4; ++j) oacc[i][j][r] *= ar;
            }
        }

        __syncthreads();                 // VT staged (vmcnt) + P visible

        // ---- O += P V : all-vector LDS reads ----
#pragma unroll
        for (int ks = 0; ks < 2; ++ks) {
            bf16x8 pa[2];                // A-frags of P: row = q = i*16+ln
#pragma unroll
            for (int i = 0; i < 2; ++i)
                pa[i] = *(const bf16x8*)&Psh[(i * 16 + ln) * 64
                                             + ((ks * 32 + qd * 8) ^ psw)];
#pragma unroll
            for (int j = 0; j < 4; ++j) {
                const int d = j * 16 + ln;
                const bf16x8 vb = *(const bf16x8*)&Vsh[d * 64
                    + ((ks * 32 + qd * 8) ^ ((ln & 7) << 3))];
#pragma unroll
                for (int i = 0; i < 2; ++i)
                    oacc[i][j] = __builtin_amdgcn_mfma_f32_16x16x32_bf16(
                        pa[i], vb, oacc[i][j], 0, 0, 0);
            }
        }
    }

    // ---- epilogue: O / l  (l lives at lane ln'=qd*4+r, shuffle it in) ----
#pragma unroll
    for (int i = 0; i < 2; ++i)
#pragma unroll
        for (int r = 0; r < 4; ++r) {
            const float lr = __shfl(l_run[i], qd * 4 + r);
            const float inv = 1.f / lr;
            const int qrow = qw0 + i * 16 + qd * 4 + r;
            u16* orow = Og + rowBase + (size_t)qrow * D_MODEL + h0 + ln;
#pragma unroll
            for (int j = 0; j < 4; ++j)
                orow[j * 16] = f2bf(oacc[i][j][r] * inv);
        }
}

// ---------------------------------------------------------------------------
static inline bool ranges_overlap(const void* a, size_t an, const void* b, size_t bn) {
    uintptr_t x0 = (uintptr_t)a, x1 = x0 + an;
    uintptr_t y0 = (uintptr_t)b, y1 = y0 + bn;
    return x0 < y1 && y0 < x1;
}

extern "C" void kernel_launch(void* const* d_in, const int* in_sizes, int n_in,
                              void* d_out, int out_size, void* d_ws, size_t ws_size,
                              hipStream_t stream)
{
    int e = 0;
    const int expect[9] = { 8388608, 1048576, 1024, 1048576, 1024,
                            1048576, 1024, 1048576, 1024 };
    if (n_in != 9) e = 59;
    if (!e) for (int i = 0; i < 9; ++i)
        if (in_sizes[i] != expect[i]) { e = 60 + i; break; }
    if (!e && out_size != (int)NXE) e = 53;
    if (!e && ranges_overlap(d_ws, ws_size, d_out, (size_t)out_size * 4)) e = 55;

    const size_t NX = NXE;
    const size_t NW = (size_t)D_MODEL * D_MODEL;
    const size_t NB = D_MODEL;

    // ws need: flag(64) + 4 weights + 4 biases + K + V = 40.0 MB (proven safe r7/r8).
    const size_t need = (64 + 4 * NW + 4 * NB + 2 * NX) * 2;
    if (!e && ws_size < need) e = 50;
    if (e) { diag_write<<<2048, 256, 0, stream>>>((float*)d_out, ldexpf(1.0f, e)); return; }

    // ws layout (u16 elems): flag | Wq Wk Wv Wo | bq bk bv bo | K | V
    u16* ws   = (u16*)d_ws;
    int* flag = (int*)ws;
    u16* Wqb  = ws + 64;
    u16* Wkb  = Wqb + NW;
    u16* Wvb  = Wkb + NW;
    u16* Wob  = Wvb + NW;
    u16* bqb  = Wob + NW;
    u16* bkb  = bqb + NB;
    u16* bvb  = bkb + NB;
    u16* bob  = bvb + NB;
    u16* Kw   = bob + NB;
    u16* Vw   = Kw  + NX;

    // Region lifetimes:
    //   d_out lower 16MB: xb (dead after gemm_qkv) -> VT (dead after flash)
    //   d_out upper 16MB: Qw (dead after flash)
    //   ws Vw: V (dead after transpose_v) -> Ow (attention output)
    //   gemm_final reads Ow (ws), writes fp32 DIRECTLY to d_out (no memcpy).
    u16* xb  = (u16*)d_out;          // x_bf16; dead after QKV gemm
    u16* Qw  = xb + NX;              // Q plane (upper half)
    u16* VTw = xb;                   // V^T reuses lower half
    u16* Ow  = Vw;                   // attention out over dead V plane

    detect_dtype<<<1, 256, 0, stream>>>((const u16*)d_in[0], flag);

    CvtArgs ca;
    const void* srcs[9] = { d_in[0], d_in[1], d_in[3], d_in[5], d_in[7],
                            d_in[2], d_in[4], d_in[6], d_in[8] };
    u16* dsts[9] = { xb, Wqb, Wkb, Wvb, Wob, bqb, bkb, bvb, bob };
    int  ns[9]   = { (int)NX, (int)NW, (int)NW, (int)NW, (int)NW,
                     (int)NB, (int)NB, (int)NB, (int)NB };
    for (int i = 0; i < 9; ++i) { ca.src[i] = srcs[i]; ca.dst[i] = dsts[i]; ca.n[i] = ns[i]; }
    cvt_all<<<dim3((unsigned)((NX + 2047) / 2048), 9), 256, 0, stream>>>(ca, flag);

    gemm_qkv<<<dim3(MTOT / 128, D_MODEL / 128, 3), 256, 0, stream>>>(
        xb, Wqb, Wkb, Wvb, bqb, bkb, bvb, Qw, Kw, Vw, MTOT, D_MODEL, D_MODEL);

    transpose_v<<<dim3(SEQ / 64, BATCH * NHEAD), 256, 0, stream>>>(Vw, VTw);

    flash_attn<<<dim3(SEQ / 32, BATCH * NHEAD), 64, 0, stream>>>(Qw, Kw, VTw, Ow);

    gemm_final_f32<<<dim3(MTOT / 128, D_MODEL / 128), 256, 0, stream>>>(
        Ow, Wob, bob, (float*)d_out, MTOT, D_MODEL, D_MODEL);
}